// Round 1
// baseline (2880.081 us; speedup 1.0000x reference)
//
#include <hip/hip_runtime.h>
#include <hip/hip_bf16.h>

#define DEV __device__ __forceinline__

typedef short short8 __attribute__((ext_vector_type(8)));
typedef float f32x4 __attribute__((ext_vector_type(4)));
typedef float v2f __attribute__((ext_vector_type(2)));
typedef unsigned short u16;

constexpr int T_ = 1024, B_ = 256, N_ = T_ * B_, D_ = 128;
constexpr int FSTR = 40;  // feat row padded to 40 bf16 (80 B, 16B-aligned rows)

DEV u16 f2b(float f) {
  unsigned u = __float_as_uint(f);
  unsigned r = (u + 0x7fffu + ((u >> 16) & 1u)) >> 16;  // RNE
  return (u16)r;
}
DEV float sigm(float x) { return 1.0f / (1.0f + __expf(-x)); }
DEV float tanh_f(float x) {
  float e = __expf(-2.0f * fabsf(x));
  float t = (1.0f - e) / (1.0f + e);
  return copysignf(t, x);
}
DEV v2f fma2(v2f a, v2f b, v2f c) {
  v2f r; r.x = fmaf(a.x, b.x, c.x); r.y = fmaf(a.y, b.y, c.y); return r;
}

// ---------------- prep: weights -> bf16, msg lookup table ----------------
__global__ void prep_kernel(const float* W1, const float* W2, const float* W3,
                            const float* W4, const float* emb, const float* msgW,
                            const float* msgb, u16* w1p, u16* w2b, u16* w3b,
                            u16* w4b, float* msgtab) {
  int i0 = blockIdx.x * blockDim.x + threadIdx.x;
  int stride = gridDim.x * blockDim.x;
  for (int i = i0; i < 256 * 32; i += stride) {  // W1 padded [256][32], K zeros past 9
    int r = i >> 5, k = i & 31;
    w1p[i] = (k < 9) ? f2b(W1[r * 9 + k]) : (u16)0;
  }
  for (int i = i0; i < 256 * 256; i += stride) w2b[i] = f2b(W2[i]);
  for (int i = i0; i < 128 * 256; i += stride) w3b[i] = f2b(W3[i]);
  for (int i = i0; i < 16 * 128; i += stride) w4b[i] = f2b(W4[i]);
  for (int i = i0; i < 256; i += stride) {  // msgtab[v][j] = relu(emb[v]·msgW[j]+b[j])
    int v = i >> 4, j = i & 15;
    float s = msgb[j];
    for (int k = 0; k < 16; ++k) s += emb[v * 16 + k] * msgW[j * 16 + k];
    msgtab[i] = s > 0.f ? s : 0.f;
  }
}

// ---------------- encoder: 64-row blocks, bf16 MFMA MLP ----------------
// A-frag: lane holds A[row=l&15][k=(l>>4)*8+e]; B-frag: B[k][col=l&15] = W[col][k]
// D: lane reg r -> D[row=(l>>4)*4+r][col=l&15]   (m89-verified layout)
template <int K, int OUTN, bool SWZIN>
DEV void mlp_layer(const u16* Ain, u16* Aout, const u16* Wb, const float* bias,
                   int colbase, int NT, int lane) {
  constexpr int KT = K / 32;
  const int lr = lane & 15, lg = lane >> 4;
  for (int nt = 0; nt < NT; ++nt) {
    const int col = colbase + nt * 16 + lr;
    short8 bf[KT];
#pragma unroll
    for (int kt = 0; kt < KT; ++kt)
      bf[kt] = *(const short8*)(Wb + col * K + kt * 32 + lg * 8);
    const float bcol = bias[col];
#pragma unroll
    for (int mt = 0; mt < 4; ++mt) {
      f32x4 acc = {0.f, 0.f, 0.f, 0.f};
#pragma unroll
      for (int kt = 0; kt < KT; ++kt) {
        const int row = mt * 16 + lr;
        int kb = (kt * 32 + lg * 8) * 2;
        if (SWZIN) kb ^= (row & 7) << 4;  // XOR swizzle vs 32-way bank conflict
        const short8 af = *(const short8*)(Ain + row * K + (kb >> 1));
        acc = __builtin_amdgcn_mfma_f32_16x16x32_bf16(af, bf[kt], acc, 0, 0, 0);
      }
#pragma unroll
      for (int r = 0; r < 4; ++r) {
        const int row = mt * 16 + lg * 4 + r;
        float v = acc[r] + bcol;
        v = v > 0.f ? v : 0.f;
        const int kb = (col * 2) ^ ((row & 7) << 4);
        Aout[row * OUTN + (kb >> 1)] = f2b(v);
      }
    }
  }
}

__global__ __launch_bounds__(256) void enc_kernel(
    const float* image, const float* location, const int* message,
    const float* vb1, const float* vb2, const float* vb3, const float* vb4,
    const float* locW, const float* locb, const u16* w1p, const u16* w2b,
    const u16* w3b, const u16* w4b, const float* msgtab, u16* featbf) {
  __shared__ __align__(16) u16 buf1[64 * 256];  // A1, then A3
  __shared__ __align__(16) u16 buf2[64 * 256];  // A0, then A2
  const int n0 = blockIdx.x * 64;
  const int tid = threadIdx.x;
  const int wave = tid >> 6, lane = tid & 63;

  for (int i = tid; i < 64 * 32; i += 256) {  // stage X/255 padded to K=32
    int r = i >> 5, k = i & 31;
    float v = (k < 9) ? image[(size_t)(n0 + r) * 9 + k] * (1.0f / 255.0f) : 0.0f;
    buf2[i] = f2b(v);
  }
  __syncthreads();
  mlp_layer<32, 256, false>(buf2, buf1, w1p, vb1, wave * 64, 4, lane);  // 9->256
  __syncthreads();
  mlp_layer<256, 256, true>(buf1, buf2, w2b, vb2, wave * 64, 4, lane);  // 256->256
  __syncthreads();
  mlp_layer<256, 128, true>(buf2, buf1, w3b, vb3, wave * 32, 2, lane);  // 256->128
  __syncthreads();
  {  // 128->16, wave handles its own 16-row M-tile
    const int lr = lane & 15, lg = lane >> 4;
    const int col = lr;
    short8 bfr[4];
#pragma unroll
    for (int kt = 0; kt < 4; ++kt)
      bfr[kt] = *(const short8*)(w4b + col * 128 + kt * 32 + lg * 8);
    f32x4 acc = {0.f, 0.f, 0.f, 0.f};
#pragma unroll
    for (int kt = 0; kt < 4; ++kt) {
      const int row = wave * 16 + lr;
      const int kb = ((kt * 32 + lg * 8) * 2) ^ ((row & 7) << 4);
      const short8 af = *(const short8*)(buf1 + row * 128 + (kb >> 1));
      acc = __builtin_amdgcn_mfma_f32_16x16x32_bf16(af, bfr[kt], acc, 0, 0, 0);
    }
    const float bcol = vb4[col];
#pragma unroll
    for (int r = 0; r < 4; ++r) {
      const int row = wave * 16 + lg * 4 + r;
      float v = acc[r] + bcol;
      v = v > 0.f ? v : 0.f;
      featbf[(size_t)(n0 + row) * FSTR + col] = f2b(v);
    }
  }
  if (tid < 64) {  // loc (linear) + msg (table) features
    const int n = n0 + tid;
    u16* fr = featbf + (size_t)n * FSTR;
    const float x0 = location[(size_t)n * 2] * 0.2f;
    const float x1 = location[(size_t)n * 2 + 1] * 0.2f;
#pragma unroll
    for (int j = 0; j < 4; ++j)
      fr[16 + j] = f2b(fmaf(x0, locW[j * 2], fmaf(x1, locW[j * 2 + 1], locb[j])));
    const float* mrow = msgtab + message[n] * 16;
#pragma unroll
    for (int j = 0; j < 16; ++j) fr[20 + j] = f2b(mrow[j]);
  }
}

// ---------------- LSTM: one block per batch row, weights in VGPRs ----------------
__global__ __launch_bounds__(256, 1) void lstm_kernel(
    const u16* featbf, const float* Whh, const float* Wih, const float* bih,
    const float* bhh, const float* done, const float* h0, const float* c0,
    u16* hidbf) {
  __shared__ float h_lds[128];
  __shared__ float fo_lds[2][128];
  __shared__ float done_lds[1024];
  const int b = blockIdx.x;
  const int t = threadIdx.x;
  const int half = t >> 7, d = t & 127;
  const int col0 = half ? 128 + d : d;        // f : i
  const int col1 = half ? 384 + d : 256 + d;  // o : g

  v2f wh0[64], wh1[64], wi0[18], wi1[18];
#pragma unroll
  for (int q = 0; q < 32; ++q) {
    float4 v = *(const float4*)&Whh[(size_t)col0 * 128 + q * 4];
    wh0[2 * q] = {v.x, v.y}; wh0[2 * q + 1] = {v.z, v.w};
    float4 u = *(const float4*)&Whh[(size_t)col1 * 128 + q * 4];
    wh1[2 * q] = {u.x, u.y}; wh1[2 * q + 1] = {u.z, u.w};
  }
#pragma unroll
  for (int q = 0; q < 9; ++q) {
    float4 v = *(const float4*)&Wih[(size_t)col0 * 36 + q * 4];
    wi0[2 * q] = {v.x, v.y}; wi0[2 * q + 1] = {v.z, v.w};
    float4 u = *(const float4*)&Wih[(size_t)col1 * 36 + q * 4];
    wi1[2 * q] = {u.x, u.y}; wi1[2 * q + 1] = {u.z, u.w};
  }
  const float bias0 = bih[col0] + bhh[col0];
  const float bias1 = bih[col1] + bhh[col1];
  for (int i = t; i < 1024; i += 256) done_lds[i] = done[(size_t)i * B_ + b];
  float c = 0.0f;
  if (t < 128) {
    h_lds[d] = h0[(size_t)b * D_ + d];
    c = c0[(size_t)b * D_ + d];
  }
  __syncthreads();

  uint4 xa[5];
  {
    const uint4* p = (const uint4*)(featbf + (size_t)b * FSTR);
#pragma unroll
    for (int q = 0; q < 5; ++q) xa[q] = p[q];
  }
  for (int step = 0; step < T_; ++step) {
    const int ns = (step + 1 < T_) ? step + 1 : step;
    const uint4* np = (const uint4*)(featbf + ((size_t)ns * B_ + b) * FSTR);
    uint4 xb[5];
#pragma unroll
    for (int q = 0; q < 5; ++q) xb[q] = np[q];  // prefetch, consumed next iter

    const float m = 1.0f - done_lds[step];
    v2f ax0 = {0.f, 0.f}, ax1 = {0.f, 0.f};
#pragma unroll
    for (int q = 0; q < 5; ++q) {
#pragma unroll
      for (int e = 0; e < 4; ++e) {
        const int j = q * 4 + e;
        if (j < 18) {
          const unsigned u = ((const unsigned*)&xa[q])[e];
          v2f xv;
          xv.x = __uint_as_float(u << 16);
          xv.y = __uint_as_float(u & 0xffff0000u);
          ax0 = fma2(wi0[j], xv, ax0);
          ax1 = fma2(wi1[j], xv, ax1);
        }
      }
    }
    v2f ah0 = {0.f, 0.f}, ah1 = {0.f, 0.f};
    const v2f* hp = (const v2f*)h_lds;
#pragma unroll
    for (int j = 0; j < 64; ++j) {
      const v2f hv = hp[j];
      ah0 = fma2(wh0[j], hv, ah0);
      ah1 = fma2(wh1[j], hv, ah1);
    }
    const float g0 = bias0 + ax0.x + ax0.y + m * (ah0.x + ah0.y);
    const float g1 = bias1 + ax1.x + ax1.y + m * (ah1.x + ah1.y);
    float iv = 0.f, gv = 0.f;
    if (half) {
      fo_lds[0][d] = sigm(g0);
      fo_lds[1][d] = sigm(g1);
    } else {
      iv = sigm(g0);
      gv = tanh_f(g1);
    }
    asm volatile("s_waitcnt lgkmcnt(0)" ::: "memory");
    __builtin_amdgcn_s_barrier();  // raw barrier: keep feat prefetch in flight
    if (!half) {
      const float f = fo_lds[0][d], o = fo_lds[1][d];
      c = fmaf(f, m * c, iv * gv);
      const float th = tanh_f(c);
      const float h = o * th;
      h_lds[d] = h;
      hidbf[((size_t)step * B_ + b) * D_ + d] = f2b(h);
    }
    asm volatile("s_waitcnt lgkmcnt(0)" ::: "memory");
    __builtin_amdgcn_s_barrier();
#pragma unroll
    for (int q = 0; q < 5; ++q) xa[q] = xb[q];
  }
}

// ---------------- heads: 4 lanes per row, shuffle-reduced ----------------
__global__ __launch_bounds__(256) void head_kernel(const u16* hidbf, const float* aW,
                                                   const float* ab, const float* hW,
                                                   const float* hb, const float* cW,
                                                   const float* cb, float* out) {
  const int tid = threadIdx.x;
  const int w = tid >> 6, l = tid & 63;
  const int r = blockIdx.x * 64 + w * 16 + (l >> 2);
  const int kq = (l & 3) * 32;
  const u16* hp = hidbf + (size_t)r * D_ + kq;
  float hx[32];
#pragma unroll
  for (int q = 0; q < 4; ++q) {
    const uint4 u = *(const uint4*)(hp + q * 8);
#pragma unroll
    for (int e = 0; e < 4; ++e) {
      const unsigned uu = ((const unsigned*)&u)[e];
      hx[q * 8 + e * 2] = __uint_as_float(uu << 16);
      hx[q * 8 + e * 2 + 1] = __uint_as_float(uu & 0xffff0000u);
    }
  }
  float acc[22];
#pragma unroll
  for (int j = 0; j < 22; ++j) {
    const float* wr = (j < 5) ? (aW + j * D_) : (j < 21 ? (hW + (j - 5) * D_) : cW);
    v2f a = {0.f, 0.f};
#pragma unroll
    for (int q = 0; q < 16; ++q) {
      const v2f wv = *(const v2f*)(wr + kq + q * 2);
      const v2f hv = {hx[q * 2], hx[q * 2 + 1]};
      a = fma2(wv, hv, a);
    }
    acc[j] = a.x + a.y;
  }
#pragma unroll
  for (int j = 0; j < 22; ++j) {
    acc[j] += __shfl_xor(acc[j], 1);
    acc[j] += __shfl_xor(acc[j], 2);
  }
  const int q = l & 3;
  float* orow = out + (size_t)r * 22;
#pragma unroll
  for (int jj = 0; jj < 5; ++jj) {
    const int j = q + jj * 4;
    const float bias = (j < 5) ? ab[j] : (j < 21 ? hb[j - 5] : cb[0]);
    orow[j] = acc[j] + bias;
  }
  if (q < 2) {
    const int j = 20 + q;
    orow[j] = acc[j] + hb[j - 5];
  }
}

extern "C" void kernel_launch(void* const* d_in, const int* in_sizes, int n_in,
                              void* d_out, int out_size, void* d_ws, size_t ws_size,
                              hipStream_t stream) {
  const float* image = (const float*)d_in[0];
  const float* location = (const float*)d_in[1];
  const int* message = (const int*)d_in[2];
  const float* done = (const float*)d_in[3];
  const float* h0 = (const float*)d_in[4];
  const float* c0 = (const float*)d_in[5];
  const float* vW1 = (const float*)d_in[6];
  const float* vb1 = (const float*)d_in[7];
  const float* vW2 = (const float*)d_in[8];
  const float* vb2 = (const float*)d_in[9];
  const float* vW3 = (const float*)d_in[10];
  const float* vb3 = (const float*)d_in[11];
  const float* vW4 = (const float*)d_in[12];
  const float* vb4 = (const float*)d_in[13];
  const float* locW = (const float*)d_in[14];
  const float* locb = (const float*)d_in[15];
  const float* emb = (const float*)d_in[16];
  const float* msgW = (const float*)d_in[17];
  const float* msgb = (const float*)d_in[18];
  const float* Wih = (const float*)d_in[19];
  const float* Whh = (const float*)d_in[20];
  const float* bih = (const float*)d_in[21];
  const float* bhh = (const float*)d_in[22];
  const float* aW = (const float*)d_in[23];
  const float* ab = (const float*)d_in[24];
  const float* hW = (const float*)d_in[25];
  const float* hb = (const float*)d_in[26];
  const float* cW = (const float*)d_in[27];
  const float* cb = (const float*)d_in[28];

  char* ws = (char*)d_ws;
  size_t off = 0;
  u16* featbf = (u16*)(ws + off); off += (size_t)N_ * FSTR * 2;  // 20.97 MB
  u16* hidbf = (u16*)(ws + off);  off += (size_t)N_ * D_ * 2;    // 67.1 MB
  u16* w1p = (u16*)(ws + off);    off += 256 * 32 * 2;
  u16* w2b = (u16*)(ws + off);    off += 256 * 256 * 2;
  u16* w3b = (u16*)(ws + off);    off += 128 * 256 * 2;
  u16* w4b = (u16*)(ws + off);    off += 16 * 128 * 2;
  float* msgtab = (float*)(ws + off); off += 256 * 4;
  (void)ws_size; (void)in_sizes; (void)n_in; (void)out_size;

  prep_kernel<<<64, 256, 0, stream>>>(vW1, vW2, vW3, vW4, emb, msgW, msgb, w1p,
                                      w2b, w3b, w4b, msgtab);
  enc_kernel<<<N_ / 64, 256, 0, stream>>>(image, location, message, vb1, vb2, vb3,
                                          vb4, locW, locb, w1p, w2b, w3b, w4b,
                                          msgtab, featbf);
  lstm_kernel<<<B_, 256, 0, stream>>>(featbf, Whh, Wih, bih, bhh, done, h0, c0,
                                      hidbf);
  head_kernel<<<N_ / 64, 256, 0, stream>>>(hidbf, aW, ab, hW, hb, cW, cb,
                                           (float*)d_out);
}

// Round 2
// 1423.038 us; speedup vs baseline: 2.0239x; 2.0239x over previous
//
#include <hip/hip_runtime.h>
#include <hip/hip_bf16.h>

#define DEV __device__ __forceinline__

typedef short short8 __attribute__((ext_vector_type(8)));
typedef _Float16 h8 __attribute__((ext_vector_type(8)));
typedef _Float16 h2 __attribute__((ext_vector_type(2)));
typedef float f32x4 __attribute__((ext_vector_type(4)));
typedef float v2f __attribute__((ext_vector_type(2)));
typedef unsigned short u16;

constexpr int T_ = 1024, B_ = 256, N_ = T_ * B_, D_ = 128;
constexpr int FS = 48;  // feat f16 row: k0-17 at pos 0-17, k18-35 at pos 24-41, rest 0

DEV u16 f2b(float f) {
  unsigned u = __float_as_uint(f);
  return (u16)((u + 0x7fffu + ((u >> 16) & 1u)) >> 16);  // RNE
}
DEV float sigm(float x) { return 1.0f / (1.0f + __expf(-x)); }
DEV float tanh_f(float x) {
  float e = __expf(-2.0f * fabsf(x));
  return copysignf((1.0f - e) / (1.0f + e), x);
}
DEV v2f fma2(v2f a, v2f b, v2f c) {
  v2f r; r.x = fmaf(a.x, b.x, c.x); r.y = fmaf(a.y, b.y, c.y); return r;
}

#if __has_builtin(__builtin_amdgcn_fdot2)
DEV float fdot2_(h2 a, h2 b, float c) { return __builtin_amdgcn_fdot2(a, b, c, false); }
#else
DEV float fdot2_(h2 a, h2 b, float c) {
  return fmaf((float)a.x, (float)b.x, fmaf((float)a.y, (float)b.y, c));
}
#endif

// ---------------- prep: weight conversion / permutation ----------------
__global__ void prep_kernel(const float* W1, const float* W2, const float* W3,
                            const float* W4, const float* emb, const float* msgW,
                            const float* msgb, const float* Wih, const float* Whh,
                            const float* bih, const float* bhh, u16* w1p, u16* w2b,
                            u16* w3b, u16* w4b, float* msgtab, _Float16* whh_h,
                            _Float16* wihp, float* biass) {
  int i0 = blockIdx.x * blockDim.x + threadIdx.x;
  int st = gridDim.x * blockDim.x;
  for (int i = i0; i < 256 * 32; i += st) {  // W1 padded [256][32]
    int r = i >> 5, k = i & 31;
    w1p[i] = (k < 9) ? f2b(W1[r * 9 + k]) : (u16)0;
  }
  for (int i = i0; i < 256 * 256; i += st) w2b[i] = f2b(W2[i]);
  for (int i = i0; i < 128 * 256; i += st) w3b[i] = f2b(W3[i]);
  for (int i = i0; i < 16 * 128; i += st) w4b[i] = f2b(W4[i]);
  for (int i = i0; i < 256; i += st) {  // msgtab[v][j] = relu(emb[v]·msgW[j]+b[j])
    int v = i >> 4, j = i & 15;
    float s = msgb[j];
    for (int k = 0; k < 16; ++k) s += emb[v * 16 + k] * msgW[j * 16 + k];
    msgtab[i] = s > 0.f ? s : 0.f;
  }
  for (int i = i0; i < 512 * 128; i += st) whh_h[i] = (_Float16)Whh[i];
  // wihp[c'][64], c' = d*4 + gate, k positions matching FS layout, zero-padded
  for (int i = i0; i < 512 * 64; i += st) {
    int c = i >> 6, p = i & 63;
    int src = (c & 3) * 128 + (c >> 2);
    float v = 0.f;
    if (p < 18) v = Wih[src * 36 + p];
    else if (p >= 24 && p < 42) v = Wih[src * 36 + p - 6];
    wihp[i] = (_Float16)v;
  }
  for (int i = i0; i < 512; i += st) {
    int src = (i & 3) * 128 + (i >> 2);
    biass[i] = bih[src] + bhh[src];
  }
}

// ---------------- encoder: 64-row blocks, bf16 MFMA MLP ----------------
template <int K, int OUTN, bool SWZIN>
DEV void mlp_layer(const u16* Ain, u16* Aout, const u16* Wb, const float* bias,
                   int colbase, int NT, int lane) {
  constexpr int KT = K / 32;
  const int lr = lane & 15, lg = lane >> 4;
  for (int nt = 0; nt < NT; ++nt) {
    const int col = colbase + nt * 16 + lr;
    short8 bf[KT];
#pragma unroll
    for (int kt = 0; kt < KT; ++kt)
      bf[kt] = *(const short8*)(Wb + col * K + kt * 32 + lg * 8);
    const float bcol = bias[col];
#pragma unroll
    for (int mt = 0; mt < 4; ++mt) {
      f32x4 acc = {0.f, 0.f, 0.f, 0.f};
#pragma unroll
      for (int kt = 0; kt < KT; ++kt) {
        const int row = mt * 16 + lr;
        int kb = (kt * 32 + lg * 8) * 2;
        if (SWZIN) kb ^= (row & 7) << 4;
        const short8 af = *(const short8*)(Ain + row * K + (kb >> 1));
        acc = __builtin_amdgcn_mfma_f32_16x16x32_bf16(af, bf[kt], acc, 0, 0, 0);
      }
#pragma unroll
      for (int r = 0; r < 4; ++r) {
        const int row = mt * 16 + lg * 4 + r;
        float v = acc[r] + bcol;
        v = v > 0.f ? v : 0.f;
        const int kb = (col * 2) ^ ((row & 7) << 4);
        Aout[row * OUTN + (kb >> 1)] = f2b(v);
      }
    }
  }
}

__global__ __launch_bounds__(256) void enc_kernel(
    const float* image, const float* location, const int* message,
    const float* vb1, const float* vb2, const float* vb3, const float* vb4,
    const float* locW, const float* locb, const u16* w1p, const u16* w2b,
    const u16* w3b, const u16* w4b, const float* msgtab, _Float16* featf) {
  __shared__ __align__(16) u16 buf1[64 * 256];
  __shared__ __align__(16) u16 buf2[64 * 256];
  const int n0 = blockIdx.x * 64;
  const int tid = threadIdx.x;
  const int wave = tid >> 6, lane = tid & 63;

  for (int i = tid; i < 64 * 32; i += 256) {  // stage X/255 padded to K=32
    int r = i >> 5, k = i & 31;
    float v = (k < 9) ? image[(size_t)(n0 + r) * 9 + k] * (1.0f / 255.0f) : 0.0f;
    buf2[i] = f2b(v);
  }
  __syncthreads();
  mlp_layer<32, 256, false>(buf2, buf1, w1p, vb1, wave * 64, 4, lane);
  __syncthreads();
  mlp_layer<256, 256, true>(buf1, buf2, w2b, vb2, wave * 64, 4, lane);
  __syncthreads();
  mlp_layer<256, 128, true>(buf2, buf1, w3b, vb3, wave * 32, 2, lane);
  __syncthreads();
  {  // 128->16
    const int lr = lane & 15, lg = lane >> 4;
    const int col = lr;
    short8 bfr[4];
#pragma unroll
    for (int kt = 0; kt < 4; ++kt)
      bfr[kt] = *(const short8*)(w4b + col * 128 + kt * 32 + lg * 8);
    f32x4 acc = {0.f, 0.f, 0.f, 0.f};
#pragma unroll
    for (int kt = 0; kt < 4; ++kt) {
      const int row = wave * 16 + lr;
      const int kb = ((kt * 32 + lg * 8) * 2) ^ ((row & 7) << 4);
      const short8 af = *(const short8*)(buf1 + row * 128 + (kb >> 1));
      acc = __builtin_amdgcn_mfma_f32_16x16x32_bf16(af, bfr[kt], acc, 0, 0, 0);
    }
    const float bcol = vb4[col];
#pragma unroll
    for (int r = 0; r < 4; ++r) {
      const int row = wave * 16 + lg * 4 + r;
      float v = acc[r] + bcol;
      v = v > 0.f ? v : 0.f;
      featf[(size_t)(n0 + row) * FS + col] = (_Float16)v;
    }
  }
  if (tid < 64) {  // loc + msg features, zero pads
    const int n = n0 + tid;
    _Float16* fr = featf + (size_t)n * FS;
#pragma unroll
    for (int j = 0; j < 6; ++j) fr[18 + j] = (_Float16)0.f;
#pragma unroll
    for (int j = 0; j < 6; ++j) fr[42 + j] = (_Float16)0.f;
    const float x0 = location[(size_t)n * 2] * 0.2f;
    const float x1 = location[(size_t)n * 2 + 1] * 0.2f;
#pragma unroll
    for (int j = 0; j < 4; ++j) {
      const int pos = (j < 2) ? 16 + j : 22 + j;  // k16,17 -> 16,17; k18,19 -> 24,25
      fr[pos] = (_Float16)fmaf(x0, locW[j * 2], fmaf(x1, locW[j * 2 + 1], locb[j]));
    }
    const float* mrow = msgtab + message[n] * 16;
#pragma unroll
    for (int j = 0; j < 16; ++j) fr[26 + j] = (_Float16)mrow[j];
  }
}

// ---------------- gx: G_x[n][c'] = feat @ W_ih'^T + (b_ih+b_hh), f16 MFMA ----------------
__global__ __launch_bounds__(256) void gx_kernel(const _Float16* featf,
                                                 const _Float16* wihp,
                                                 const float* biass, _Float16* gx) {
  __shared__ __align__(16) u16 a_lds[64 * 64];  // f16 bits, swizzled, K padded to 64
  const int n0 = blockIdx.x * 64;
  const int tid = threadIdx.x;
  for (int grp = tid; grp < 64 * 8; grp += 256) {
    const int row = grp >> 3, k0 = (grp & 7) * 8;
    short8 v = {0, 0, 0, 0, 0, 0, 0, 0};
    if (k0 < 48) v = *(const short8*)(featf + (size_t)(n0 + row) * FS + k0);
    const int byte = (row * 128 + k0 * 2) ^ ((row & 7) << 4);
    *(short8*)((char*)a_lds + byte) = v;
  }
  __syncthreads();
  const int wave = tid >> 6, lane = tid & 63;
  const int lr = lane & 15, lg = lane >> 4;
  h8 bfr[8][2];
#pragma unroll
  for (int nt = 0; nt < 8; ++nt) {
    const int col = wave * 128 + nt * 16 + lr;
#pragma unroll
    for (int kt = 0; kt < 2; ++kt)
      bfr[nt][kt] = *(const h8*)(wihp + (size_t)col * 64 + kt * 32 + lg * 8);
  }
  for (int mt = 0; mt < 4; ++mt) {
    const int arow = mt * 16 + lr;
    h8 af[2];
#pragma unroll
    for (int kt = 0; kt < 2; ++kt) {
      const int byte = (arow * 128 + (kt * 32 + lg * 8) * 2) ^ ((arow & 7) << 4);
      af[kt] = *(const h8*)((char*)a_lds + byte);
    }
    f32x4 acc[8];
#pragma unroll
    for (int nt = 0; nt < 8; ++nt) acc[nt] = f32x4{0.f, 0.f, 0.f, 0.f};
#pragma unroll
    for (int nt = 0; nt < 8; ++nt)
#pragma unroll
      for (int kt = 0; kt < 2; ++kt)
        acc[nt] = __builtin_amdgcn_mfma_f32_16x16x32_f16(af[kt], bfr[nt][kt],
                                                         acc[nt], 0, 0, 0);
#pragma unroll
    for (int nt = 0; nt < 8; ++nt) {
      const int col = wave * 128 + nt * 16 + lr;
      const float bsum = biass[col];
#pragma unroll
      for (int q = 0; q < 4; ++q) {
        const int row = mt * 16 + lg * 4 + q;
        gx[(size_t)(n0 + row) * 512 + col] = (_Float16)(acc[nt][q] + bsum);
      }
    }
  }
}

// ---------------- LSTM: 1 block/row, K-split pairs, f16 dot2, 1 barrier/step ----------------
template <int XDOT>
__global__ __launch_bounds__(256, 1) void lstm_kernel(
    const _Float16* gx, const _Float16* featf, const _Float16* whh_h,
    const _Float16* wihp, const float* biass, const float* done, const float* h0,
    const float* c0, u16* hidbf) {
  __shared__ __align__(16) _Float16 hbuf[2][128];
  __shared__ float m_lds[1024];
  const int b = blockIdx.x;
  const int tid = threadIdx.x;
  const int w = tid >> 6, l = tid & 63;
  const int d = w * 32 + (l & 31);
  const int kh = l >> 5;  // K-half: this thread covers h[kh*64 .. kh*64+64)

  // W_hh slice: 4 gates x 64 halves = 128 VGPRs of f16 pairs
  h2 wh[4][32];
#pragma unroll
  for (int g = 0; g < 4; ++g) {
    const h2* p = (const h2*)(whh_h + ((size_t)(g * 128 + d) * 128 + kh * 64));
#pragma unroll
    for (int j = 0; j < 32; ++j) wh[g][j] = p[j];
  }
  h2 wx[4][12];
  float bs4[4] = {0.f, 0.f, 0.f, 0.f};
  if (XDOT) {
#pragma unroll
    for (int g = 0; g < 4; ++g) {
      const h2* p = (const h2*)(wihp + ((size_t)(d * 4 + g) * 64 + kh * 24));
#pragma unroll
      for (int j = 0; j < 12; ++j) wx[g][j] = p[j];
      bs4[g] = biass[d * 4 + g];
    }
  }
  for (int i = tid; i < 1024; i += 256) m_lds[i] = 1.0f - done[(size_t)i * B_ + b];
  float c = c0[(size_t)b * D_ + d];
  if (tid < 128) hbuf[0][tid] = (_Float16)h0[(size_t)b * D_ + tid];
  __syncthreads();

  uint2 gq = {0, 0};
  h2 xq[12];
  if (!XDOT) {
    if (kh == 0) gq = *(const uint2*)(gx + ((size_t)b * 512 + (size_t)d * 4));
  } else {
    const h2* p = (const h2*)(featf + ((size_t)b * FS + kh * 24));
#pragma unroll
    for (int j = 0; j < 12; ++j) xq[j] = p[j];
  }
  int pb = 0;
  for (int step = 0; step < T_; ++step) {
    // prefetch next step's x-input (stays in flight across the barrier)
    const int ns = (step + 1 < T_) ? step + 1 : step;
    uint2 gn = {0, 0};
    h2 xn[12];
    if (!XDOT) {
      if (kh == 0) gn = *(const uint2*)(gx + (((size_t)ns * B_ + b) * 512 + (size_t)d * 4));
    } else {
      const h2* p = (const h2*)(featf + (((size_t)ns * B_ + b) * FS + kh * 24));
#pragma unroll
      for (int j = 0; j < 12; ++j) xn[j] = p[j];
    }
    const float m = m_lds[step];
    h2 hv[32];
    const h2* hp = (const h2*)&hbuf[pb][kh * 64];
#pragma unroll
    for (int j = 0; j < 32; ++j) hv[j] = hp[j];
    float a0 = 0.f, a1 = 0.f, a2 = 0.f, a3 = 0.f;
#pragma unroll
    for (int j = 0; j < 32; ++j) {
      a0 = fdot2_(wh[0][j], hv[j], a0);
      a1 = fdot2_(wh[1][j], hv[j], a1);
      a2 = fdot2_(wh[2][j], hv[j], a2);
      a3 = fdot2_(wh[3][j], hv[j], a3);
    }
    float u0, u1, u2, u3;
    if (XDOT) {
      float x0 = 0.f, x1 = 0.f, x2 = 0.f, x3 = 0.f;
#pragma unroll
      for (int j = 0; j < 12; ++j) {
        x0 = fdot2_(wx[0][j], xq[j], x0);
        x1 = fdot2_(wx[1][j], xq[j], x1);
        x2 = fdot2_(wx[2][j], xq[j], x2);
        x3 = fdot2_(wx[3][j], xq[j], x3);
      }
      const float bb = (kh == 0) ? 1.f : 0.f;
      u0 = fmaf(bb, bs4[0], x0 + m * a0);
      u1 = fmaf(bb, bs4[1], x1 + m * a1);
      u2 = fmaf(bb, bs4[2], x2 + m * a2);
      u3 = fmaf(bb, bs4[3], x3 + m * a3);
    } else {
      if (kh == 0) {
        const h2 p01 = __builtin_bit_cast(h2, gq.x);
        const h2 p23 = __builtin_bit_cast(h2, gq.y);
        u0 = (float)p01.x + m * a0;
        u1 = (float)p01.y + m * a1;
        u2 = (float)p23.x + m * a2;
        u3 = (float)p23.y + m * a3;
      } else {
        u0 = m * a0; u1 = m * a1; u2 = m * a2; u3 = m * a3;
      }
    }
    const float g0 = u0 + __shfl_xor(u0, 32);
    const float g1 = u1 + __shfl_xor(u1, 32);
    const float g2 = u2 + __shfl_xor(u2, 32);
    const float g3 = u3 + __shfl_xor(u3, 32);
    const float iv = sigm(g0), fv = sigm(g1), gv = tanh_f(g2), ov = sigm(g3);
    c = fmaf(fv, m * c, iv * gv);
    const float h = ov * tanh_f(c);
    if (kh == 0) {
      hbuf[pb ^ 1][d] = (_Float16)h;
      hidbf[((size_t)step * B_ + b) * D_ + d] = f2b(h);
    }
    asm volatile("s_waitcnt lgkmcnt(0)" ::: "memory");
    __builtin_amdgcn_s_barrier();
    pb ^= 1;
    gq = gn;
#pragma unroll
    for (int j = 0; j < 12; ++j) xq[j] = xn[j];
  }
}

// ---------------- heads: 4 lanes per row, shuffle-reduced ----------------
__global__ __launch_bounds__(256) void head_kernel(const u16* hidbf, const float* aW,
                                                   const float* ab, const float* hW,
                                                   const float* hb, const float* cW,
                                                   const float* cb, float* out) {
  const int tid = threadIdx.x;
  const int w = tid >> 6, l = tid & 63;
  const int r = blockIdx.x * 64 + w * 16 + (l >> 2);
  const int kq = (l & 3) * 32;
  const u16* hp = hidbf + (size_t)r * D_ + kq;
  float hx[32];
#pragma unroll
  for (int q = 0; q < 4; ++q) {
    const uint4 u = *(const uint4*)(hp + q * 8);
#pragma unroll
    for (int e = 0; e < 4; ++e) {
      const unsigned uu = ((const unsigned*)&u)[e];
      hx[q * 8 + e * 2] = __uint_as_float(uu << 16);
      hx[q * 8 + e * 2 + 1] = __uint_as_float(uu & 0xffff0000u);
    }
  }
  float acc[22];
#pragma unroll
  for (int j = 0; j < 22; ++j) {
    const float* wr = (j < 5) ? (aW + j * D_) : (j < 21 ? (hW + (j - 5) * D_) : cW);
    v2f a = {0.f, 0.f};
#pragma unroll
    for (int q = 0; q < 16; ++q) {
      const v2f wv = *(const v2f*)(wr + kq + q * 2);
      const v2f hv = {hx[q * 2], hx[q * 2 + 1]};
      a = fma2(wv, hv, a);
    }
    acc[j] = a.x + a.y;
  }
#pragma unroll
  for (int j = 0; j < 22; ++j) {
    acc[j] += __shfl_xor(acc[j], 1);
    acc[j] += __shfl_xor(acc[j], 2);
  }
  const int q = l & 3;
  float* orow = out + (size_t)r * 22;
#pragma unroll
  for (int jj = 0; jj < 5; ++jj) {
    const int j = q + jj * 4;
    const float bias = (j < 5) ? ab[j] : (j < 21 ? hb[j - 5] : cb[0]);
    orow[j] = acc[j] + bias;
  }
  if (q < 2) {
    const int j = 20 + q;
    orow[j] = acc[j] + hb[j - 5];
  }
}

extern "C" void kernel_launch(void* const* d_in, const int* in_sizes, int n_in,
                              void* d_out, int out_size, void* d_ws, size_t ws_size,
                              hipStream_t stream) {
  const float* image = (const float*)d_in[0];
  const float* location = (const float*)d_in[1];
  const int* message = (const int*)d_in[2];
  const float* done = (const float*)d_in[3];
  const float* h0 = (const float*)d_in[4];
  const float* c0 = (const float*)d_in[5];
  const float* vW1 = (const float*)d_in[6];
  const float* vb1 = (const float*)d_in[7];
  const float* vW2 = (const float*)d_in[8];
  const float* vb2 = (const float*)d_in[9];
  const float* vW3 = (const float*)d_in[10];
  const float* vb3 = (const float*)d_in[11];
  const float* vW4 = (const float*)d_in[12];
  const float* vb4 = (const float*)d_in[13];
  const float* locW = (const float*)d_in[14];
  const float* locb = (const float*)d_in[15];
  const float* emb = (const float*)d_in[16];
  const float* msgW = (const float*)d_in[17];
  const float* msgb = (const float*)d_in[18];
  const float* Wih = (const float*)d_in[19];
  const float* Whh = (const float*)d_in[20];
  const float* bih = (const float*)d_in[21];
  const float* bhh = (const float*)d_in[22];
  const float* aW = (const float*)d_in[23];
  const float* ab = (const float*)d_in[24];
  const float* hW = (const float*)d_in[25];
  const float* hb = (const float*)d_in[26];
  const float* cW = (const float*)d_in[27];
  const float* cb = (const float*)d_in[28];

  char* ws = (char*)d_ws;
  size_t off = 0;
  auto alloc = [&](size_t bytes) {
    void* p = ws + off;
    off = (off + bytes + 255) & ~(size_t)255;
    return p;
  };
  _Float16* featf = (_Float16*)alloc((size_t)N_ * FS * 2);   // 25.2 MB
  u16* hidbf = (u16*)alloc((size_t)N_ * D_ * 2);             // 67.1 MB
  u16* w1p = (u16*)alloc(256 * 32 * 2);
  u16* w2b = (u16*)alloc(256 * 256 * 2);
  u16* w3b = (u16*)alloc(128 * 256 * 2);
  u16* w4b = (u16*)alloc(16 * 128 * 2);
  float* msgtab = (float*)alloc(256 * 4);
  _Float16* whh_h = (_Float16*)alloc(512 * 128 * 2);
  _Float16* wihp = (_Float16*)alloc(512 * 64 * 2);
  float* biass = (float*)alloc(512 * 4);
  size_t off_gx = off;
  _Float16* gx = (_Float16*)(ws + off_gx);
  const bool use_gx = (off_gx + (size_t)N_ * 512 * 2) <= ws_size;  // +268 MB
  (void)in_sizes; (void)n_in; (void)out_size;

  prep_kernel<<<64, 256, 0, stream>>>(vW1, vW2, vW3, vW4, emb, msgW, msgb, Wih,
                                      Whh, bih, bhh, w1p, w2b, w3b, w4b, msgtab,
                                      whh_h, wihp, biass);
  enc_kernel<<<N_ / 64, 256, 0, stream>>>(image, location, message, vb1, vb2, vb3,
                                          vb4, locW, locb, w1p, w2b, w3b, w4b,
                                          msgtab, featf);
  if (use_gx) {
    gx_kernel<<<N_ / 64, 256, 0, stream>>>(featf, wihp, biass, gx);
    lstm_kernel<0><<<B_, 256, 0, stream>>>(gx, featf, whh_h, wihp, biass, done,
                                           h0, c0, hidbf);
  } else {
    lstm_kernel<1><<<B_, 256, 0, stream>>>(gx, featf, whh_h, wihp, biass, done,
                                           h0, c0, hidbf);
  }
  head_kernel<<<N_ / 64, 256, 0, stream>>>(hidbf, aW, ab, hW, hb, cW, cb,
                                           (float*)d_out);
}